// Round 18
// baseline (124.285 us; speedup 1.0000x reference)
//
#include <hip/hip_runtime.h>
#include <hip/hip_bf16.h>
#include <math.h>

typedef __attribute__((ext_vector_type(8))) short short8;
typedef __attribute__((ext_vector_type(8))) __bf16 bf16x8;
typedef __attribute__((ext_vector_type(4))) float f32x4;
typedef __attribute__((ext_vector_type(16))) float f32x16;

#define D_MODEL 1024
#define NUM_HEADS 16
#define D_HEAD 64
#define BATCH 2
#define SEQ 2048
#define BH (BATCH * NUM_HEADS)   // 32
#define MTOT (BATCH * SEQ)       // 4096

__device__ inline f32x4 mfma16(short8 a, short8 b, f32x4 c) {
  return __builtin_amdgcn_mfma_f32_16x16x32_bf16(
      __builtin_bit_cast(bf16x8, a), __builtin_bit_cast(bf16x8, b), c, 0, 0, 0);
}

__device__ inline f32x16 mfma32(short8 a, short8 b, f32x16 c) {
  return __builtin_amdgcn_mfma_f32_32x32x16_bf16(
      __builtin_bit_cast(bf16x8, a), __builtin_bit_cast(bf16x8, b), c, 0, 0, 0);
}

__device__ inline unsigned short f2b(float f) {
  __hip_bfloat16 h = __float2bfloat16(f);
  return __builtin_bit_cast(unsigned short, h);
}

__device__ inline unsigned cvt_pk_bf16(float lo, float hi) {
  unsigned r;
  asm("v_cvt_pk_bf16_f32 %0, %1, %2" : "=v"(r) : "v"(lo), "v"(hi));
  return r;
}

// hardware 2^x (v_exp_f32); 2^-inf = 0 for masked lanes
__device__ inline float exp2_hw(float x) {
  float r;
  asm("v_exp_f32 %0, %1" : "=v"(r) : "v"(x));
  return r;
}

// swap a's high 32 lanes with b's low 32 lanes
__device__ inline void permlane32_swap(unsigned& a, unsigned& b) {
  asm("v_permlane32_swap_b32 %0, %1" : "+v"(a), "+v"(b));
}

// single drain+barrier per K-tile (m248 2-phase minimum)
__device__ __forceinline__ void wait_barrier_vm0() {
  asm volatile("s_waitcnt vmcnt(0)\n\ts_barrier" ::: "memory");
}

#define GLOAD_LDS16(gaddr, laddr)                                              \
  __builtin_amdgcn_global_load_lds(                                            \
      (const __attribute__((address_space(1))) void*)(gaddr),                  \
      (__attribute__((address_space(3))) void*)(laddr), 16, 0, 0)

// ---------------- fused prep: x->bf16, 4 weights->bf16, trig table ---------
__global__ void prep(const float* __restrict__ x,
                     const float* __restrict__ Wq, const float* __restrict__ Wk,
                     const float* __restrict__ Wv, const float* __restrict__ Wo,
                     unsigned short* __restrict__ xb,
                     unsigned short* __restrict__ wqkv,
                     unsigned short* __restrict__ wob,
                     float2* __restrict__ tct) {
  const int bid = blockIdx.x;
  if (bid < 8192) {
    const float* in;
    unsigned short* out;
    int lb;
    if (bid < 4096) {
      in = x; out = xb; lb = bid;
    } else {
      const int q = (bid - 4096) >> 10;   // 0..3
      lb = (bid - 4096) & 1023;
      in = (q == 0) ? Wq : (q == 1) ? Wk : (q == 2) ? Wv : Wo;
      out = (q < 3) ? wqkv + (size_t)q * 1048576 : wob;
    }
    int i = (lb * 256 + threadIdx.x) * 4;
    float4 v = *(const float4*)(in + i);
    ushort4 o;
    o.x = f2b(v.x); o.y = f2b(v.y); o.z = f2b(v.z); o.w = f2b(v.w);
    *(ushort4*)(out + i) = o;
  } else {
    int idx = (bid - 8192) * 256 + threadIdx.x;  // SEQ*32 = 65536
    int i = idx & 31;
    int s = idx >> 5;
    float inv = powf(10000.0f, -(float)i / 32.0f);
    float t = (float)s * inv;
    tct[idx] = make_float2(cosf(t), sinf(t));
  }
}

// ---- BK=64 staging: linear LDS dest, XOR-swizzled GLOBAL source ----
#define STAGE64(t, bufi)                                                        \
  do {                                                                          \
    const int _k0 = (t) * 64;                                                   \
    const int _gc = ((lane & 7) ^ (lane >> 3)) * 8;                             \
    const int _lc = (lane & 7) * 8;                                             \
    for (int j = 0; j < 4; j++) {                                               \
      const int _r = w * 32 + j * 8 + (lane >> 3);                              \
      GLOAD_LDS16(&A[(size_t)(bm + _r) * D_MODEL + _k0 + _gc], &As[bufi][_r][_lc]); \
      GLOAD_LDS16(&Bp[(size_t)(bn + _r) * D_MODEL + _k0 + _gc], &Bs[bufi][_r][_lc]); \
    }                                                                           \
  } while (0)

// 2-phase pipelined K-loop: ONE vmcnt(0)+barrier per K-tile
#define KLOOP64()                                                               \
  do {                                                                          \
    const int NT = D_MODEL / 64;                                                \
    STAGE64(0, 0);                                                              \
    for (int t = 0; t < NT; ++t) {                                              \
      const int cur = t & 1;                                                    \
      wait_barrier_vm0();                                                       \
      if (t + 1 < NT) STAGE64(t + 1, cur ^ 1);                                  \
      for (int kk = 0; kk < 2; kk++) {                                          \
        short8 af[4], bf4[4];                                                   \
        for (int mi = 0; mi < 4; mi++)                                          \
          af[mi] = *(const short8*)&As[cur][wr + mi * 16 + fr]                  \
                                         [(kk * 32 + fk) ^ ((fr & 7) << 3)];    \
        for (int ni = 0; ni < 4; ni++)                                          \
          bf4[ni] = *(const short8*)&Bs[cur][wc + ni * 16 + fr]                 \
                                          [(kk * 32 + fk) ^ ((fr & 7) << 3)];   \
        __builtin_amdgcn_s_setprio(1);                                          \
        for (int mi = 0; mi < 4; mi++)                                          \
          for (int ni = 0; ni < 4; ni++)                                        \
            acc[mi][ni] = mfma16(af[mi], bf4[ni], acc[mi][ni]);                 \
        __builtin_amdgcn_s_setprio(0);                                          \
      }                                                                         \
    }                                                                           \
  } while (0)

// ---------------- merged QKV GEMM (R5-verified, 46us) ----------------
__global__ __launch_bounds__(256) void gemm_qkv(
    const unsigned short* __restrict__ A,     // [M,1024] bf16
    const unsigned short* __restrict__ Bp,    // Wqkv [3072,1024] bf16
    const float* __restrict__ bq, const float* __restrict__ bk,
    const float* __restrict__ bv,
    const float2* __restrict__ tct,
    unsigned short* __restrict__ Qb, unsigned short* __restrict__ Kb,
    unsigned short* __restrict__ Vt) {
  __shared__ unsigned short As[2][128][64];
  __shared__ unsigned short Bs[2][128][64];
  const int bm = blockIdx.y * 128;
  const int bn = blockIdx.x * 128;
  const int tid = threadIdx.x;
  const int lane = tid & 63;
  const int w = tid >> 6;
  const int wr = (w >> 1) * 64, wc = (w & 1) * 64;
  const int fr = lane & 15;
  const int g = lane >> 4;
  const int fk = g * 8;

  f32x4 acc[4][4] = {};
  KLOOP64();

  const int type = bn >> 10;         // block-uniform
  const int cloc = (bn & 1023) + wc; // col within the 1024 group
  if (type <= 1) {
    const float* bias = (type == 0) ? bq : bk;
    unsigned short* outp = (type == 0) ? Qb : Kb;
    // Q gets softmax scale AND log2(e) folded in (flash uses exp2)
    const float SC = (type == 0) ? 0.125f * 1.44269504f : 1.0f;
    const int h = cloc >> 6;
    for (int mi = 0; mi < 4; mi++)
      for (int r = 0; r < 4; r++) {
        int row = bm + wr + mi * 16 + g * 4 + r;
        int b = row >> 11, s = row & (SEQ - 1);
        size_t base = (((size_t)(b * NUM_HEADS + h)) * SEQ + s) * 64;
        for (int ni = 0; ni < 2; ni++) {
          int i = ni * 16 + fr;  // dh in [0,32)
          float x0 = acc[mi][ni][r] + bias[cloc + i];
          float x1 = acc[mi][ni + 2][r] + bias[cloc + i + 32];
          float2 cs = tct[s * 32 + i];
          outp[base + i]      = f2b((x0 * cs.x - x1 * cs.y) * SC);
          outp[base + i + 32] = f2b((x1 * cs.x + x0 * cs.y) * SC);
        }
      }
  } else {
    for (int mi = 0; mi < 4; mi++) {
      int row0 = bm + wr + mi * 16 + g * 4;   // 4 consecutive s, same b
      int b = row0 >> 11, s0 = row0 & (SEQ - 1);
      for (int ni = 0; ni < 4; ni++) {
        int col = cloc + ni * 16 + fr;
        int h = col >> 6, dh = col & 63;
        float bvv = bv[col];
        uint2 pk = make_uint2(
            cvt_pk_bf16(acc[mi][ni][0] + bvv, acc[mi][ni][1] + bvv),
            cvt_pk_bf16(acc[mi][ni][2] + bvv, acc[mi][ni][3] + bvv));
        *(uint2*)&Vt[(((size_t)(b * NUM_HEADS + h)) * 64 + dh) * SEQ + s0] = pk;
      }
    }
  }
}

// ---------------- output GEMM: out[M,1024] = ctx @ Wo^T + bo (fp32) --------
__global__ __launch_bounds__(256) void gemm_out(
    const unsigned short* __restrict__ A,   // ctx bf16 [M,1024]
    const unsigned short* __restrict__ Bp,  // Wo bf16 [1024,1024]
    const float* __restrict__ bias,
    float* __restrict__ outf) {
  __shared__ unsigned short As[2][128][64];
  __shared__ unsigned short Bs[2][128][64];
  const int bm = blockIdx.y * 128;
  const int bn = blockIdx.x * 128;
  const int tid = threadIdx.x;
  const int lane = tid & 63;
  const int w = tid >> 6;
  const int wr = (w >> 1) * 64, wc = (w & 1) * 64;
  const int fr = lane & 15;
  const int g = lane >> 4;
  const int fk = g * 8;

  f32x4 acc[4][4] = {};
  KLOOP64();

  for (int mi = 0; mi < 4; mi++)
    for (int ni = 0; ni < 4; ni++)
      for (int r = 0; r < 4; r++) {
        int row = bm + wr + mi * 16 + g * 4 + r;
        int col = bn + wc + ni * 16 + fr;
        outf[(size_t)row * D_MODEL + col] = acc[mi][ni][r] + bias[col];
      }
}

// ---------------- causal flash attention v11: dual-tile-per-wave ----------
// 256 threads = 4 waves; grid (32 bh, 8 by) = 256 blocks (32 KB LDS -> ~3
// blocks/CU). Each wave owns TWO 32-row strips: heavy tile (15-by) and light
// tile (by), computed against the SAME staged K/V tile in the same step ->
// light work fills heavy's stream instead of waves idling (R13 was 68% slot
// utilization). Work per wave = 34 tile-steps uniform. Inner tile math and
// R12 staging geometry verified; two statically-named accumulator sets.
#define FTILE(qrow0_, q_, qf_, o0_, o1_, lq_)                                  \
  if (kbase <= qrow0_ + 31) {                                                  \
    for (int kt = 0; kt < 2; kt++) {                                           \
      const int ktb = kbase + kt * 32;                                         \
      if (ktb <= qrow0_ + 31) {   /* wave-uniform */                           \
        f32x16 sacc = {};                                                      \
        const int krow = kt * 32 + q31;                                        \
        const int kro = krow * 64;                                             \
        const int ksw = krow & 7;                                              \
        for (int s = 0; s < 4; s++) {                                          \
          short8 kf = *(const short8*)&Ks[cur][kro + (((s * 2 + hi) ^ ksw) * 8)]; \
          sacc = mfma32(kf, qf_[s], sacc);                                     \
        }                                                                      \
        const bool maskT = (ktb + 31 > qrow0_);                                \
        float p[16];                                                           \
        float rs = 0.f;                                                        \
        _Pragma("unroll")                                                      \
        for (int reg = 0; reg < 16; reg++) {                                   \
          float sv = sacc[reg];                                                \
          if (maskT) {                                                         \
            int key = ktb + (reg & 3) + 8 * (reg >> 2) + 4 * hi;               \
            sv = (key <= q_) ? sv : -INFINITY;                                 \
          }                                                                    \
          p[reg] = exp2_hw(sv);                                                \
          rs += p[reg];                                                        \
        }                                                                      \
        lq_ += rs;                                                             \
        short8 paf[2];                                                         \
        _Pragma("unroll")                                                      \
        for (int sl = 0; sl < 2; sl++) {                                       \
          const int o = sl * 8;                                                \
          unsigned a0 = cvt_pk_bf16(p[o + 0], p[o + 1]);                       \
          unsigned b0 = cvt_pk_bf16(p[o + 4], p[o + 5]);                       \
          permlane32_swap(a0, b0);                                             \
          unsigned a1 = cvt_pk_bf16(p[o + 2], p[o + 3]);                       \
          unsigned b1 = cvt_pk_bf16(p[o + 6], p[o + 7]);                       \
          permlane32_swap(a1, b1);                                             \
          uint4 u = make_uint4(a0, a1, b0, b1);                                \
          paf[sl] = __builtin_bit_cast(short8, u);                             \
        }                                                                      \
        _Pragma("unroll")                                                      \
        for (int dt = 0; dt < 2; dt++) {                                       \
          const int vrow = dt * 32 + q31;                                      \
          const int vro = vrow * 64;                                           \
          const int vsw = vrow & 7;                                            \
          _Pragma("unroll")                                                    \
          for (int sl = 0; sl < 2; sl++) {                                     \
            short8 vf = *(const short8*)&Vs[cur][vro + (((kt * 4 + sl * 2 + hi) ^ vsw) * 8)]; \
            if (dt == 0) o0_ = mfma32(paf[sl], vf, o0_);                       \
            else         o1_ = mfma32(paf[sl], vf, o1_);                       \
          }                                                                    \
        }                                                                      \
      }                                                                        \
    }                                                                          \
  }

__global__ __launch_bounds__(256) void flash_attn(
    const unsigned short* __restrict__ Q,
    const unsigned short* __restrict__ Km,
    const unsigned short* __restrict__ Vt,
    unsigned short* __restrict__ ctx) {
  __shared__ unsigned short Ks[2][64 * 64];   // [key][dh] swizzled
  __shared__ unsigned short Vs[2][64 * 64];   // [dh][key] swizzled
  const int bh = blockIdx.x;
  const int by = blockIdx.y;                  // 0..7
  const int tid = threadIdx.x;
  const int lane = tid & 63;
  const int w = tid >> 6;        // 0..3
  const int q31 = lane & 31;
  const int hi = lane >> 5;

  const unsigned short* Qp = Q + (size_t)bh * SEQ * 64;
  const unsigned short* Kp = Km + (size_t)bh * SEQ * 64;
  const unsigned short* Vp = Vt + (size_t)bh * 64 * SEQ;
  const int b = bh >> 4, h = bh & 15;

  const int qtH = 15 - by, qtL = by;
  const int qrow0H = qtH * 128 + w * 32;
  const int qrow0L = qtL * 128 + w * 32;
  const int qH = qrow0H + q31;
  const int qL = qrow0L + q31;

  short8 qfH[4], qfL[4];
#pragma unroll
  for (int s = 0; s < 4; s++) {
    qfH[s] = *(const short8*)&Qp[(size_t)qH * 64 + s * 16 + hi * 8];
    qfL[s] = *(const short8*)&Qp[(size_t)qL * 64 + s * 16 + hi * 8];
  }

  // staging (R12 geometry): row = tid>>2, two 16B slots, swizzled dest
  const int srow = tid >> 2;
  const int ss0 = (tid & 3) * 2, ss1 = ss0 + 1;
  const int lw0 = srow * 64 + ((ss0 ^ (srow & 7)) * 8);
  const int lw1 = srow * 64 + ((ss1 ^ (srow & 7)) * 8);

  short8 krA = *(const short8*)&Kp[(size_t)srow * 64 + ss0 * 8];
  short8 krB = *(const short8*)&Kp[(size_t)srow * 64 + ss1 * 8];
  short8 vrA = *(const short8*)&Vp[(size_t)srow * SEQ + ss0 * 8];
  short8 vrB = *(const short8*)&Vp[(size_t)srow * SEQ + ss1 * 8];

  f32x16 oH0 = {}, oH1 = {}, oL0 = {}, oL1 = {};
  float lqH = 0.f, lqL = 0.f;
  const int NSTEPS = 2 * qtH + 2;   // heavy tile's step count (covers light)

  for (int step = 0; step < NSTEPS; ++step) {
    const int kbase = step * 64;
    const int cur = step & 1;
    *(short8*)&Ks[cur][lw0] = krA;
    *(short8*)&Ks[cur][lw1] = krB;
    *(short8*)&Vs[cur][lw0] = vrA;
    *(short8*)&Vs[cur][lw1] = vrB;
    __syncthreads();   // single barrier per step (dbuf covers trailing hazard)
    if (step + 1 < NSTEPS) {
      const int nk = kbase + 64;
      krA = *(const short8*)&Kp[(size_t)(nk + srow) * 64 + ss0 * 8];
      krB = *(const short8*)&Kp[(size_t)(nk + srow) * 64 + ss1 * 8];
      vrA = *(const short8*)&Vp[(size_t)srow * SEQ + nk + ss0 * 8];
      vrB = *(const short8*)&Vp[(size_t)srow * SEQ + nk + ss1 * 8];
    }

    FTILE(qrow0H, qH, qfH, oH0, oH1, lqH);
    FTILE(qrow0L, qL, qfL, oL0, oL1, lqL);
  }

  lqH += __shfl_xor(lqH, 32);
  lqL += __shfl_xor(lqL, 32);
#pragma unroll
  for (int reg = 0; reg < 16; reg++) {
    const int crow = (reg & 3) + 8 * (reg >> 2) + 4 * hi;
    const float linvH = 1.f / __shfl(lqH, crow);
    const float linvL = 1.f / __shfl(lqL, crow);
    const int rowH = qrow0H + crow;
    const int rowL = qrow0L + crow;
    size_t baseH = ((size_t)b * SEQ + rowH) * D_MODEL + h * 64 + q31;
    size_t baseL = ((size_t)b * SEQ + rowL) * D_MODEL + h * 64 + q31;
    ctx[baseH]      = f2b(oH0[reg] * linvH);
    ctx[baseH + 32] = f2b(oH1[reg] * linvH);
    ctx[baseL]      = f2b(oL0[reg] * linvL);
    ctx[baseL + 32] = f2b(oL1[reg] * linvL);
  }
}

extern "C" void kernel_launch(void* const* d_in, const int* in_sizes, int n_in,
                              void* d_out, int out_size, void* d_ws, size_t ws_size,
                              hipStream_t stream) {
  const float* x  = (const float*)d_in[0];
  const float* Wq = (const float*)d_in[1];
  const float* bq = (const float*)d_in[2];
  const float* Wk = (const float*)d_in[3];
  const float* bk = (const float*)d_in[4];
  const float* Wv = (const float*)d_in[5];
  const float* bv = (const float*)d_in[6];
  const float* Wo = (const float*)d_in[7];
  const float* bo = (const float*)d_in[8];
  float* out = (float*)d_out;

  char* ws = (char*)d_ws;
  size_t off = 0;
  auto alloc = [&](size_t bytes) {
    char* p = ws + off;
    off += (bytes + 255) & ~(size_t)255;
    return p;
  };
  unsigned short* xb   = (unsigned short*)alloc((size_t)MTOT * D_MODEL * 2);
  unsigned short* wqkv = (unsigned short*)alloc((size_t)3 * D_MODEL * D_MODEL * 2);
  unsigned short* wob  = (unsigned short*)alloc((size_t)D_MODEL * D_MODEL * 2);
  unsigned short* Qb   = (unsigned short*)alloc((size_t)BH * SEQ * 64 * 2);
  unsigned short* Kb   = (unsigned short*)alloc((size_t)BH * SEQ * 64 * 2);
  unsigned short* Vt   = (unsigned short*)alloc((size_t)BH * 64 * SEQ * 2);
  unsigned short* ctxb = (unsigned short*)alloc((size_t)MTOT * D_MODEL * 2);
  float2* tct = (float2*)alloc((size_t)SEQ * 32 * 8);

  prep<<<8448, 256, 0, stream>>>(x, Wq, Wk, Wv, Wo, xb, wqkv, wob, tct);

  gemm_qkv<<<dim3(3 * D_MODEL / 128, MTOT / 128), 256, 0, stream>>>(
      xb, wqkv, bq, bk, bv, tct, Qb, Kb, Vt);

  flash_attn<<<dim3(BH, 8), 256, 0, stream>>>(Qb, Kb, Vt, ctxb);

  gemm_out<<<dim3(D_MODEL / 128, MTOT / 128), 256, 0, stream>>>(ctxb, wob, bo, out);
}

// Round 19
// 115.255 us; speedup vs baseline: 1.0783x; 1.0783x over previous
//
#include <hip/hip_runtime.h>
#include <hip/hip_bf16.h>
#include <math.h>

typedef __attribute__((ext_vector_type(8))) short short8;
typedef __attribute__((ext_vector_type(8))) __bf16 bf16x8;
typedef __attribute__((ext_vector_type(4))) float f32x4;
typedef __attribute__((ext_vector_type(16))) float f32x16;

#define D_MODEL 1024
#define NUM_HEADS 16
#define D_HEAD 64
#define BATCH 2
#define SEQ 2048
#define BH (BATCH * NUM_HEADS)   // 32
#define MTOT (BATCH * SEQ)       // 4096

__device__ inline f32x4 mfma16(short8 a, short8 b, f32x4 c) {
  return __builtin_amdgcn_mfma_f32_16x16x32_bf16(
      __builtin_bit_cast(bf16x8, a), __builtin_bit_cast(bf16x8, b), c, 0, 0, 0);
}

__device__ inline f32x16 mfma32(short8 a, short8 b, f32x16 c) {
  return __builtin_amdgcn_mfma_f32_32x32x16_bf16(
      __builtin_bit_cast(bf16x8, a), __builtin_bit_cast(bf16x8, b), c, 0, 0, 0);
}

__device__ inline unsigned short f2b(float f) {
  __hip_bfloat16 h = __float2bfloat16(f);
  return __builtin_bit_cast(unsigned short, h);
}

__device__ inline unsigned cvt_pk_bf16(float lo, float hi) {
  unsigned r;
  asm("v_cvt_pk_bf16_f32 %0, %1, %2" : "=v"(r) : "v"(lo), "v"(hi));
  return r;
}

// hardware 2^x (v_exp_f32); 2^-inf = 0 for masked lanes
__device__ inline float exp2_hw(float x) {
  float r;
  asm("v_exp_f32 %0, %1" : "=v"(r) : "v"(x));
  return r;
}

// swap a's high 32 lanes with b's low 32 lanes
__device__ inline void permlane32_swap(unsigned& a, unsigned& b) {
  asm("v_permlane32_swap_b32 %0, %1" : "+v"(a), "+v"(b));
}

// single drain+barrier per K-tile (m248 2-phase minimum)
__device__ __forceinline__ void wait_barrier_vm0() {
  asm volatile("s_waitcnt vmcnt(0)\n\ts_barrier" ::: "memory");
}

#define GLOAD_LDS16(gaddr, laddr)                                              \
  __builtin_amdgcn_global_load_lds(                                            \
      (const __attribute__((address_space(1))) void*)(gaddr),                  \
      (__attribute__((address_space(3))) void*)(laddr), 16, 0, 0)

// ---------------- fused prep: x->bf16, 4 weights->bf16, trig table ---------
// blocks [0,4096): x (4 els/thread); [4096,8192): weights (1024 blocks each
// of Wq,Wk,Wv,Wo); [8192,8448): RoPE (cos,sin) table.
__global__ void prep(const float* __restrict__ x,
                     const float* __restrict__ Wq, const float* __restrict__ Wk,
                     const float* __restrict__ Wv, const float* __restrict__ Wo,
                     unsigned short* __restrict__ xb,
                     unsigned short* __restrict__ wqkv,
                     unsigned short* __restrict__ wob,
                     float2* __restrict__ tct) {
  const int bid = blockIdx.x;
  if (bid < 8192) {
    const float* in;
    unsigned short* out;
    int lb;
    if (bid < 4096) {
      in = x; out = xb; lb = bid;
    } else {
      const int q = (bid - 4096) >> 10;   // 0..3
      lb = (bid - 4096) & 1023;
      in = (q == 0) ? Wq : (q == 1) ? Wk : (q == 2) ? Wv : Wo;
      out = (q < 3) ? wqkv + (size_t)q * 1048576 : wob;
    }
    int i = (lb * 256 + threadIdx.x) * 4;
    float4 v = *(const float4*)(in + i);
    ushort4 o;
    o.x = f2b(v.x); o.y = f2b(v.y); o.z = f2b(v.z); o.w = f2b(v.w);
    *(ushort4*)(out + i) = o;
  } else {
    int idx = (bid - 8192) * 256 + threadIdx.x;  // SEQ*32 = 65536
    int i = idx & 31;
    int s = idx >> 5;
    float inv = powf(10000.0f, -(float)i / 32.0f);
    float t = (float)s * inv;
    tct[idx] = make_float2(cosf(t), sinf(t));
  }
}

// ---- BK=64 staging: linear LDS dest, XOR-swizzled GLOBAL source ----
#define STAGE64(t, bufi)                                                        \
  do {                                                                          \
    const int _k0 = (t) * 64;                                                   \
    const int _gc = ((lane & 7) ^ (lane >> 3)) * 8;                             \
    const int _lc = (lane & 7) * 8;                                             \
    for (int j = 0; j < 4; j++) {                                               \
      const int _r = w * 32 + j * 8 + (lane >> 3);                              \
      GLOAD_LDS16(&A[(size_t)(bm + _r) * D_MODEL + _k0 + _gc], &As[bufi][_r][_lc]); \
      GLOAD_LDS16(&Bp[(size_t)(bn + _r) * D_MODEL + _k0 + _gc], &Bs[bufi][_r][_lc]); \
    }                                                                           \
  } while (0)

// 2-phase pipelined K-loop: ONE vmcnt(0)+barrier per K-tile
#define KLOOP64()                                                               \
  do {                                                                          \
    const int NT = D_MODEL / 64;                                                \
    STAGE64(0, 0);                                                              \
    for (int t = 0; t < NT; ++t) {                                              \
      const int cur = t & 1;                                                    \
      wait_barrier_vm0();                                                       \
      if (t + 1 < NT) STAGE64(t + 1, cur ^ 1);                                  \
      for (int kk = 0; kk < 2; kk++) {                                          \
        short8 af[4], bf4[4];                                                   \
        for (int mi = 0; mi < 4; mi++)                                          \
          af[mi] = *(const short8*)&As[cur][wr + mi * 16 + fr]                  \
                                         [(kk * 32 + fk) ^ ((fr & 7) << 3)];    \
        for (int ni = 0; ni < 4; ni++)                                          \
          bf4[ni] = *(const short8*)&Bs[cur][wc + ni * 16 + fr]                 \
                                          [(kk * 32 + fk) ^ ((fr & 7) << 3)];   \
        __builtin_amdgcn_s_setprio(1);                                          \
        for (int mi = 0; mi < 4; mi++)                                          \
          for (int ni = 0; ni < 4; ni++)                                        \
            acc[mi][ni] = mfma16(af[mi], bf4[ni], acc[mi][ni]);                 \
        __builtin_amdgcn_s_setprio(0);                                          \
      }                                                                         \
    }                                                                           \
  } while (0)

// ---------------- merged QKV GEMM (R5-verified, 46us) ----------------
__global__ __launch_bounds__(256) void gemm_qkv(
    const unsigned short* __restrict__ A,     // [M,1024] bf16
    const unsigned short* __restrict__ Bp,    // Wqkv [3072,1024] bf16
    const float* __restrict__ bq, const float* __restrict__ bk,
    const float* __restrict__ bv,
    const float2* __restrict__ tct,
    unsigned short* __restrict__ Qb, unsigned short* __restrict__ Kb,
    unsigned short* __restrict__ Vt) {
  __shared__ unsigned short As[2][128][64];
  __shared__ unsigned short Bs[2][128][64];
  const int bm = blockIdx.y * 128;
  const int bn = blockIdx.x * 128;
  const int tid = threadIdx.x;
  const int lane = tid & 63;
  const int w = tid >> 6;
  const int wr = (w >> 1) * 64, wc = (w & 1) * 64;
  const int fr = lane & 15;
  const int g = lane >> 4;
  const int fk = g * 8;

  f32x4 acc[4][4] = {};
  KLOOP64();

  const int type = bn >> 10;         // block-uniform
  const int cloc = (bn & 1023) + wc; // col within the 1024 group
  if (type <= 1) {
    const float* bias = (type == 0) ? bq : bk;
    unsigned short* outp = (type == 0) ? Qb : Kb;
    // Q gets softmax scale AND log2(e) folded in (flash uses exp2)
    const float SC = (type == 0) ? 0.125f * 1.44269504f : 1.0f;
    const int h = cloc >> 6;
    for (int mi = 0; mi < 4; mi++)
      for (int r = 0; r < 4; r++) {
        int row = bm + wr + mi * 16 + g * 4 + r;
        int b = row >> 11, s = row & (SEQ - 1);
        size_t base = (((size_t)(b * NUM_HEADS + h)) * SEQ + s) * 64;
        for (int ni = 0; ni < 2; ni++) {
          int i = ni * 16 + fr;  // dh in [0,32)
          float x0 = acc[mi][ni][r] + bias[cloc + i];
          float x1 = acc[mi][ni + 2][r] + bias[cloc + i + 32];
          float2 cs = tct[s * 32 + i];
          outp[base + i]      = f2b((x0 * cs.x - x1 * cs.y) * SC);
          outp[base + i + 32] = f2b((x1 * cs.x + x0 * cs.y) * SC);
        }
      }
  } else {
    for (int mi = 0; mi < 4; mi++) {
      int row0 = bm + wr + mi * 16 + g * 4;   // 4 consecutive s, same b
      int b = row0 >> 11, s0 = row0 & (SEQ - 1);
      for (int ni = 0; ni < 4; ni++) {
        int col = cloc + ni * 16 + fr;
        int h = col >> 6, dh = col & 63;
        float bvv = bv[col];
        uint2 pk = make_uint2(
            cvt_pk_bf16(acc[mi][ni][0] + bvv, acc[mi][ni][1] + bvv),
            cvt_pk_bf16(acc[mi][ni][2] + bvv, acc[mi][ni][3] + bvv));
        *(uint2*)&Vt[(((size_t)(b * NUM_HEADS + h)) * 64 + dh) * SEQ + s0] = pk;
      }
    }
  }
}

// ---------------- output GEMM: out[M,1024] = ctx @ Wo^T + bo (fp32) --------
__global__ __launch_bounds__(256) void gemm_out(
    const unsigned short* __restrict__ A,   // ctx bf16 [M,1024]
    const unsigned short* __restrict__ Bp,  // Wo bf16 [1024,1024]
    const float* __restrict__ bias,
    float* __restrict__ outf) {
  __shared__ unsigned short As[2][128][64];
  __shared__ unsigned short Bs[2][128][64];
  const int bm = blockIdx.y * 128;
  const int bn = blockIdx.x * 128;
  const int tid = threadIdx.x;
  const int lane = tid & 63;
  const int w = tid >> 6;
  const int wr = (w >> 1) * 64, wc = (w & 1) * 64;
  const int fr = lane & 15;
  const int g = lane >> 4;
  const int fk = g * 8;

  f32x4 acc[4][4] = {};
  KLOOP64();

  for (int mi = 0; mi < 4; mi++)
    for (int ni = 0; ni < 4; ni++)
      for (int r = 0; r < 4; r++) {
        int row = bm + wr + mi * 16 + g * 4 + r;
        int col = bn + wc + ni * 16 + fr;
        outf[(size_t)row * D_MODEL + col] = acc[mi][ni][r] + bias[col];
      }
}

// ---------------- causal flash attention (R13-verified paired tiles) -------
// 512 threads = 8 waves. Waves 0-3 -> q-tile (15-by) [heavy], waves 4-7 ->
// q-tile (by) [light]; both share the staged K/V tiles and the barrier loop
// (light's kv-range is a subset of heavy's). Per-block work = 34 step-
// equivalents for EVERY by -> uniform blocks; grid (32,8) = 256 = 1/CU.
// Per-wave tile math identical to verified R12: dbuf single-barrier loop,
// swapped QK^T (mfma32), in-register P via cvt_pk+permlane32_swap,
// exp2-no-max softmax, XOR-swizzled K/V.
__global__ __launch_bounds__(512) void flash_attn(
    const unsigned short* __restrict__ Q,
    const unsigned short* __restrict__ Km,
    const unsigned short* __restrict__ Vt,
    unsigned short* __restrict__ ctx) {
  __shared__ unsigned short Ks[2][64 * 64];   // [key][dh] swizzled
  __shared__ unsigned short Vs[2][64 * 64];   // [dh][key] swizzled
  const int bh = blockIdx.x;
  const int by = blockIdx.y;                  // 0..7
  const int tid = threadIdx.x;
  const int lane = tid & 63;
  const int w = tid >> 6;        // 0..7
  const int gi = w >> 2;         // 0 = heavy group, 1 = light group
  const int wl = w & 3;          // wave-in-group
  const int q31 = lane & 31;
  const int hi = lane >> 5;

  const unsigned short* Qp = Q + (size_t)bh * SEQ * 64;
  const unsigned short* Kp = Km + (size_t)bh * SEQ * 64;
  const unsigned short* Vp = Vt + (size_t)bh * 64 * SEQ;
  const int b = bh >> 4, h = bh & 15;

  const int qt = gi ? by : (15 - by);         // light : heavy
  const int qbase = qt * 128;
  const int qrow0 = qbase + wl * 32;
  const int wmax = qrow0 + 31;
  const int q = qrow0 + q31;     // this lane's q-row

  short8 qf[4];
  for (int s = 0; s < 4; s++)
    qf[s] = *(const short8*)&Qp[(size_t)q * 64 + s * 16 + hi * 8];

  // staging: 512 threads, one 16B K-slot + one 16B V-slot each
  const int srow = tid >> 3;            // 0..63
  const int ss = tid & 7;               // slot 0..7
  const int lw = srow * 64 + ((ss ^ (srow & 7)) * 8);

  short8 kr = *(const short8*)&Kp[(size_t)srow * 64 + ss * 8];
  short8 vr = *(const short8*)&Vp[(size_t)srow * SEQ + ss * 8];

  f32x16 oacc0 = {}, oacc1 = {};
  float lq = 0.f;
  const int NSTEPS = 2 * (15 - by) + 2;   // heavy tile's step count

  for (int step = 0; step < NSTEPS; ++step) {
    const int kbase = step * 64;
    const int cur = step & 1;
    *(short8*)&Ks[cur][lw] = kr;
    *(short8*)&Vs[cur][lw] = vr;
    __syncthreads();   // single barrier per step (dbuf covers trailing hazard)
    if (step + 1 < NSTEPS) {
      const int nk = kbase + 64;
      kr = *(const short8*)&Kp[(size_t)(nk + srow) * 64 + ss * 8];
      vr = *(const short8*)&Vp[(size_t)srow * SEQ + nk + ss * 8];
    }

    if (kbase <= wmax) {   // wave-uniform (light waves retire early)
      for (int kt = 0; kt < 2; kt++) {
        const int ktb = kbase + kt * 32;
        if (ktb <= wmax) {   // wave-uniform
          f32x16 sacc = {};
          const int krow = kt * 32 + q31;
          const int kro = krow * 64;
          const int ksw = krow & 7;
          for (int s = 0; s < 4; s++) {
            short8 kf = *(const short8*)&Ks[cur][kro + (((s * 2 + hi) ^ ksw) * 8)];
            sacc = mfma32(kf, qf[s], sacc);
          }
          const bool maskT = (ktb + 31 > qrow0);
          float p[16];
          float rs = 0.f;
#pragma unroll
          for (int reg = 0; reg < 16; reg++) {
            float sv = sacc[reg];
            if (maskT) {
              int key = ktb + (reg & 3) + 8 * (reg >> 2) + 4 * hi;
              sv = (key <= q) ? sv : -INFINITY;
            }
            p[reg] = exp2_hw(sv);
            rs += p[reg];
          }
          lq += rs;
          short8 paf[2];
#pragma unroll
          for (int sl = 0; sl < 2; sl++) {
            const int o = sl * 8;
            unsigned a0 = cvt_pk_bf16(p[o + 0], p[o + 1]);
            unsigned b0 = cvt_pk_bf16(p[o + 4], p[o + 5]);
            permlane32_swap(a0, b0);
            unsigned a1 = cvt_pk_bf16(p[o + 2], p[o + 3]);
            unsigned b1 = cvt_pk_bf16(p[o + 6], p[o + 7]);
            permlane32_swap(a1, b1);
            uint4 u = make_uint4(a0, a1, b0, b1);
            paf[sl] = __builtin_bit_cast(short8, u);
          }
#pragma unroll
          for (int dt = 0; dt < 2; dt++) {
            const int vrow = dt * 32 + q31;
            const int vro = vrow * 64;
            const int vsw = vrow & 7;
#pragma unroll
            for (int sl = 0; sl < 2; sl++) {
              short8 vf = *(const short8*)&Vs[cur][vro + (((kt * 4 + sl * 2 + hi) ^ vsw) * 8)];
              if (dt == 0) oacc0 = mfma32(paf[sl], vf, oacc0);
              else         oacc1 = mfma32(paf[sl], vf, oacc1);
            }
          }
        }
      }
    }
  }

  lq += __shfl_xor(lq, 32);
#pragma unroll
  for (int reg = 0; reg < 16; reg++) {
    const int crow = (reg & 3) + 8 * (reg >> 2) + 4 * hi;
    const float linv = 1.f / __shfl(lq, crow);
    const int row = qrow0 + crow;
    size_t base = ((size_t)b * SEQ + row) * D_MODEL + h * 64 + q31;
    ctx[base]      = f2b(oacc0[reg] * linv);
    ctx[base + 32] = f2b(oacc1[reg] * linv);
  }
}

extern "C" void kernel_launch(void* const* d_in, const int* in_sizes, int n_in,
                              void* d_out, int out_size, void* d_ws, size_t ws_size,
                              hipStream_t stream) {
  const float* x  = (const float*)d_in[0];
  const float* Wq = (const float*)d_in[1];
  const float* bq = (const float*)d_in[2];
  const float* Wk = (const float*)d_in[3];
  const float* bk = (const float*)d_in[4];
  const float* Wv = (const float*)d_in[5];
  const float* bv = (const float*)d_in[6];
  const float* Wo = (const float*)d_in[7];
  const float* bo = (const float*)d_in[8];
  float* out = (float*)d_out;

  char* ws = (char*)d_ws;
  size_t off = 0;
  auto alloc = [&](size_t bytes) {
    char* p = ws + off;
    off += (bytes + 255) & ~(size_t)255;
    return p;
  };
  unsigned short* xb   = (unsigned short*)alloc((size_t)MTOT * D_MODEL * 2);
  unsigned short* wqkv = (unsigned short*)alloc((size_t)3 * D_MODEL * D_MODEL * 2);
  unsigned short* wob  = (unsigned short*)alloc((size_t)D_MODEL * D_MODEL * 2);
  unsigned short* Qb   = (unsigned short*)alloc((size_t)BH * SEQ * 64 * 2);
  unsigned short* Kb   = (unsigned short*)alloc((size_t)BH * SEQ * 64 * 2);
  unsigned short* Vt   = (unsigned short*)alloc((size_t)BH * 64 * SEQ * 2);
  unsigned short* ctxb = (unsigned short*)alloc((size_t)MTOT * D_MODEL * 2);
  float2* tct = (float2*)alloc((size_t)SEQ * 32 * 8);

  prep<<<8448, 256, 0, stream>>>(x, Wq, Wk, Wv, Wo, xb, wqkv, wob, tct);

  gemm_qkv<<<dim3(3 * D_MODEL / 128, MTOT / 128), 256, 0, stream>>>(
      xb, wqkv, bq, bk, bv, tct, Qb, Kb, Vt);

  flash_attn<<<dim3(BH, 8), 512, 0, stream>>>(Qb, Kb, Vt, ctxb);

  gemm_out<<<dim3(D_MODEL / 128, MTOT / 128), 256, 0, stream>>>(ctxb, wob, bo, out);
}